// Round 6
// baseline (268.805 us; speedup 1.0000x reference)
//
#include <hip/hip_runtime.h>
#include <stdint.h>

#define S_LEN 2048
#define HIDDEN 1024
#define NHEADS 16
#define NKVH 4
#define HDIM 64

typedef __bf16 bf16x8 __attribute__((ext_vector_type(8)));
typedef __bf16 bf16x4 __attribute__((ext_vector_type(4)));
typedef float f32x4 __attribute__((ext_vector_type(4)));
typedef short s16x4 __attribute__((ext_vector_type(4)));
typedef unsigned short U16;

// ---- workspace layout (bf16 elems) -----------------------------------------
#define OFF_XB   0u          // 8192*1024 (aliased by aws later)
#define OFF_WQB  8388608u
#define OFF_WKB  9437184u
#define OFF_WVB  9699328u
#define OFF_WOB  9961472u
#define OFF_Q    11010048u
#define OFF_K    19398656u
#define OFF_V    21495808u   // V^T TILED: [b][hkv][s>>6][d][s&63]  (8KB-contiguous tiles)
#define OFF_AWS  OFF_XB

static __device__ __forceinline__ U16 f2bf(float f){
    unsigned u;
    __builtin_memcpy(&u, &f, 4);
    u += 0x7FFFu + ((u >> 16) & 1u);   // RNE
    return (U16)(u >> 16);
}
static __device__ __forceinline__ uint32_t pkbf(float lo, float hi){
    uint32_t a, b;
    __builtin_memcpy(&a, &lo, 4); a += 0x7FFFu + ((a >> 16) & 1u);
    __builtin_memcpy(&b, &hi, 4); b += 0x7FFFu + ((b >> 16) & 1u);
    return (a >> 16) | (b & 0xFFFF0000u);
}

typedef __attribute__((address_space(3))) uint32_t lds_u32;
typedef const __attribute__((address_space(1))) uint32_t glb_u32;
static __device__ __forceinline__ void glds16(const U16* g, U16* l){
    __builtin_amdgcn_global_load_lds((glb_u32*)g, (lds_u32*)l, 16, 0, 0);
}

// ---------------------------------------------------------------------------
// Kernel 0: fp32 -> bf16 convert of X, Wq, Wk, Wv, Wo into workspace.
// ---------------------------------------------------------------------------
__global__ void conv_kernel(const float* __restrict__ X,  const float* __restrict__ Wq,
                            const float* __restrict__ Wk, const float* __restrict__ Wv,
                            const float* __restrict__ Wo, U16* __restrict__ dst)
{
    size_t i4 = (size_t)blockIdx.x * 256 + threadIdx.x;
    size_t e = i4 * 4;
    const float* s;
    if (e < 8388608u)       s = X  + e;
    else if (e < 9437184u)  s = Wq + (e - 8388608u);
    else if (e < 9699328u)  s = Wk + (e - 9437184u);
    else if (e < 9961472u)  s = Wv + (e - 9699328u);
    else                    s = Wo + (e - 9961472u);
    float4 v = *(const float4*)s;
    uint2 o; o.x = pkbf(v.x, v.y); o.y = pkbf(v.z, v.w);
    *(uint2*)(dst + e) = o;
}

// ---------------------------------------------------------------------------
// Kernel 1: QKV GEMM (NT) + bias + RoPE. BK=64, glds16 + XOR chunk-swizzle.
// grid(64,12): mblk = blockIdx.x (fast) -> XCD partition for L2 locality.
// Q pre-scaled by 0.125*log2(e). V written to TILED-transposed ws (UNPERMUTED
// -- R5's in-row key permutation caused partial-line scatter writes whose L2
// dirty-line writebacks+refetches billed ~24 MB of HBM traffic to attn).
// ---------------------------------------------------------------------------
__global__ __launch_bounds__(256, 3)
void qkv_kernel(const U16* __restrict__ Xb,
                const U16* __restrict__ Wqb, const U16* __restrict__ Wkb, const U16* __restrict__ Wvb,
                const float* __restrict__ bq, const float* __restrict__ bk, const float* __restrict__ bv,
                const float* __restrict__ cosT, const float* __restrict__ sinT,
                U16* __restrict__ qws, U16* __restrict__ kws, U16* __restrict__ vtws)
{
    __shared__ __align__(16) U16 Asm[128 * 64];
    __shared__ __align__(16) U16 Bsm[128 * 64];

    const int mblk = blockIdx.x;   // 0..63  (fast axis -> XCD partition)
    const int nblk = blockIdx.y;   // 0..11
    const int tid  = threadIdx.x;
    const int wave = tid >> 6, lane = tid & 63;
    const int ln = lane & 15, quad = lane >> 4;
    const int wm = wave >> 1, wn = wave & 1;

    const U16* Wp; const float* biasp; int region;
    const int nbase = nblk * 128;
    if (nblk < 8)       { Wp = Wqb + (size_t)nbase * HIDDEN;          biasp = bq + nbase;          region = 0; }
    else if (nblk < 10) { Wp = Wkb + (size_t)(nbase - 1024) * HIDDEN; biasp = bk + (nbase - 1024); region = 1; }
    else                { Wp = Wvb + (size_t)(nbase - 1280) * HIDDEN; biasp = bv + (nbase - 1280); region = 2; }
    const U16* Xp = Xb + (size_t)mblk * 128 * HIDDEN;

    f32x4 acc[4][4];
    #pragma unroll
    for (int i = 0; i < 4; i++)
        #pragma unroll
        for (int j = 0; j < 4; j++) acc[i][j] = (f32x4){0.f, 0.f, 0.f, 0.f};

    const int l8 = lane >> 3;
    const int cg = (lane & 7) ^ l8;
    const int sw = ln & 7;

    for (int k0 = 0; k0 < HIDDEN; k0 += 64) {
        __syncthreads();
        #pragma unroll
        for (int t = 0; t < 4; t++) {
            int rbase = wave * 32 + t * 8;
            glds16(Xp + (size_t)(rbase + l8) * HIDDEN + k0 + cg * 8, &Asm[rbase * 64]);
            glds16(Wp + (size_t)(rbase + l8) * HIDDEN + k0 + cg * 8, &Bsm[rbase * 64]);
        }
        __syncthreads();

        bf16x8 af[4][2], bfr[4][2];
        #pragma unroll
        for (int i = 0; i < 4; i++)
            #pragma unroll
            for (int ks = 0; ks < 2; ks++) {
                af[i][ks]  = *(const bf16x8*)(&Asm[(wm * 64 + i * 16 + ln) * 64 + (((ks * 4 + quad) ^ sw) * 8)]);
                bfr[i][ks] = *(const bf16x8*)(&Bsm[(wn * 64 + i * 16 + ln) * 64 + (((ks * 4 + quad) ^ sw) * 8)]);
            }
        #pragma unroll
        for (int i = 0; i < 4; i++)
            #pragma unroll
            for (int j = 0; j < 4; j++) {
                acc[i][j] = __builtin_amdgcn_mfma_f32_16x16x32_bf16(af[i][0], bfr[j][0], acc[i][j], 0, 0, 0);
                acc[i][j] = __builtin_amdgcn_mfma_f32_16x16x32_bf16(af[i][1], bfr[j][1], acc[i][j], 0, 0, 0);
            }
    }

    float bias[4];
    #pragma unroll
    for (int j = 0; j < 4; j++) bias[j] = biasp[wn * 64 + j * 16 + ln];

    const float QSCALE = 0.125f * 1.44269504089f;

    if (region == 2) {
        // V -> tiled transposed ws: r-index = consecutive s -> 8B coalesced stores
        #pragma unroll
        for (int i = 0; i < 4; i++) {
            int m0 = mblk * 128 + wm * 64 + i * 16 + quad * 4;   // r=0 row
            int b = m0 >> 11;
            int st6 = m0 & (S_LEN - 1);
            int tile = st6 >> 6, soff = st6 & 63;
            #pragma unroll
            for (int j = 0; j < 4; j++) {
                int n2 = nbase - 1280 + wn * 64 + j * 16 + ln;
                int hh = n2 >> 6, d = n2 & 63;
                uint2 w;
                w.x = pkbf(acc[i][j][0] + bias[j], acc[i][j][1] + bias[j]);
                w.y = pkbf(acc[i][j][2] + bias[j], acc[i][j][3] + bias[j]);
                *(uint2*)(vtws + ((((size_t)b * NKVH + hh) * 32 + tile) * 64 + d) * 64 + soff) = w;
            }
        }
    } else {
        #pragma unroll
        for (int i = 0; i < 4; i++) {
            #pragma unroll
            for (int r = 0; r < 4; r++) {
                int m = mblk * 128 + wm * 64 + i * 16 + quad * 4 + r;
                int s = m & (S_LEN - 1), b = m >> 11;
                float vals[4];
                #pragma unroll
                for (int j = 0; j < 4; j++) vals[j] = acc[i][j][r] + bias[j];
                float outv[4];
                #pragma unroll
                for (int j = 0; j < 4; j++) {
                    int d = (wn * 64 + j * 16 + ln) & 63;
                    float c  = cosT[s * HDIM + d];
                    float sn = sinT[s * HDIM + d];
                    float partner = vals[j ^ 2];
                    float rot = (d < 32) ? -partner : partner;
                    outv[j] = vals[j] * c + rot * sn;
                }
                if (region == 0) {  // Q (scaled)
                    #pragma unroll
                    for (int j = 0; j < 4; j++) {
                        int n = nbase + wn * 64 + j * 16 + ln;
                        int hh = n >> 6, d = n & 63;
                        qws[(((size_t)b * NHEADS + hh) * S_LEN + s) * HDIM + d] = f2bf(outv[j] * QSCALE);
                    }
                } else {            // K
                    #pragma unroll
                    for (int j = 0; j < 4; j++) {
                        int n2 = nbase - 1024 + wn * 64 + j * 16 + ln;
                        int hh = n2 >> 6, d = n2 & 63;
                        kws[(((size_t)b * NKVH + hh) * S_LEN + s) * HDIM + d] = f2bf(outv[j]);
                    }
                }
            }
        }
    }
}

// ---------------------------------------------------------------------------
// Kernel 2: flash attention, fixed-max softmax. QBLK=128, 64-key tiles,
// glds16-staged double-buffered K and V^T (unpermuted), ONE barrier/tile.
//
// ROUND 6: keep K=32 PV (R5 confirmed _1k costs full matrix-pipe occupancy:
// MFMA cycles 44us -> 29us when 32 PV _1k -> 16 K=32 MFMAs). Drop the V ws
// permutation (caused the R5 HBM anomaly: +24 MB parasitic writeback/refetch
// billed to attn). The 8 keys a lane holds after QK over a 2-j-block pair
// ({pr*32+quad*4+e, pr*32+16+quad*4+e}) are exactly TWO aligned 8-byte chunks
// of the UNPERMUTED V^T tile: chunks (pr*4+(quad>>1))^sw and
// (pr*4+2+(quad>>1))^sw at byte-offset (quad&1)*4 -- R4's two b64 addresses.
// So build each K=32 A-fragment from two ds_read_b64. Zero shuffles.
// Pipeline: [QK(pr)+PV(pr-1) MFMA cluster, setprio] -> [LDS reads for next
// stage] -> [sched_barrier] -> [exp2/pack of z(pr)].
// ---------------------------------------------------------------------------
__global__ __launch_bounds__(256, 4)
void attn_kernel(const U16* __restrict__ qws, const U16* __restrict__ kws,
                 const U16* __restrict__ vtws, U16* __restrict__ aws)
{
    __shared__ __align__(16) U16 Ksm[2][64 * 64];    // 16 KB
    __shared__ __align__(16) U16 VTsm[2][64 * 64];   // 16 KB

    const int qt = blockIdx.x;       // 0..15 (QBLK = 128)
    const int hg = blockIdx.y;
    const int b = hg >> 4, h = hg & 15, hkv = h >> 2;
    const U16* Qh  = qws  + (size_t)hg * S_LEN * HDIM;
    const U16* Kh  = kws  + (size_t)(b * NKVH + hkv) * S_LEN * HDIM;
    const U16* VTh = vtws + (size_t)(b * NKVH + hkv) * HDIM * S_LEN;   // 32 tiles x 4096

    const int tid = threadIdx.x;
    const int wave = tid >> 6, lane = tid & 63;
    const int ln = lane & 15, quad = lane >> 4;
    const int sw = ln & 7;
    const int voff = (quad & 1) * 4;

    // Q fragments (B-operand, resident): two 16-row blocks per wave
    bf16x8 qf[2][2];
    #pragma unroll
    for (int i = 0; i < 2; i++)
        #pragma unroll
        for (int ks = 0; ks < 2; ks++) {
            int row = qt * 128 + wave * 32 + i * 16 + ln;
            qf[i][ks] = *(const bf16x8*)(Qh + (size_t)row * HDIM + ks * 32 + quad * 8);
        }

    float rsA[2] = {0.f, 0.f}, rsB[2] = {0.f, 0.f};
    f32x4 o_t[4][2];
    #pragma unroll
    for (int n = 0; n < 4; n++)
        #pragma unroll
        for (int i = 0; i < 2; i++) o_t[n][i] = (f32x4){0.f, 0.f, 0.f, 0.f};

    const int l8 = lane >> 3;
    const int cgk = (lane & 7) ^ l8;

    // loop-invariant per-lane LDS element offsets
    const int koff0 = ln * 64 + ((quad ^ sw) * 8);           // + j*1024
    const int koff1 = ln * 64 + (((quad + 4) ^ sw) * 8);     // + j*1024
    const int vrow = ln * 64;                                 // + n*1024 + chunk

    // incremental glds source pointers (tile stride = 4096 elems both)
    const U16* pk[2]; const U16* pv[2];
    U16* dK[2]; U16* dV[2];
    #pragma unroll
    for (int t = 0; t < 2; t++) {
        int c = wave * 2 + t;
        pk[t] = Kh  + (size_t)(c * 8 + l8) * HDIM + cgk * 8;
        pv[t] = VTh + (size_t)(c * 8 + l8) * 64  + cgk * 8;
        dK[t] = &Ksm[0][c * 8 * 64];
        dV[t] = &VTsm[0][c * 8 * 64];
    }

    // prologue: stage tile 0
    #pragma unroll
    for (int t = 0; t < 2; t++) {
        glds16(pk[t], dK[t]);
        glds16(pv[t], dV[t]);
        pk[t] += 4096; pv[t] += 4096;
    }

    // software-pipeline state (zero-primed: first PV accumulates 0)
    bf16x8 pfp[2];
    #pragma unroll
    for (int i = 0; i < 2; i++) pfp[i] = (bf16x8){0,0,0,0,0,0,0,0};
    bf16x8 vfp[4];
    #pragma unroll
    for (int n = 0; n < 4; n++) vfp[n] = (bf16x8){0,0,0,0,0,0,0,0};

    int p = 0;
    for (int kt = 0; kt < 32; kt++) {
        __syncthreads();   // drains glds (tile kt ready in [p]); [p^1] free

        if (kt < 31) {     // prefetch tile kt+1 (flies under compute)
            #pragma unroll
            for (int t = 0; t < 2; t++) {
                glds16(pk[t], dK[t] + (p ^ 1) * 4096);
                glds16(pv[t], dV[t] + (p ^ 1) * 4096);
                pk[t] += 4096; pv[t] += 4096;
            }
        }

        const U16* Kb = &Ksm[p][0];
        const U16* Vb = &VTsm[p][0];

        // preload K fragments for pair 0 (j-blocks 0,1)
        bf16x8 kf[2][2];
        kf[0][0] = *(const bf16x8*)(Kb + koff0);
        kf[0][1] = *(const bf16x8*)(Kb + koff1);
        kf[1][0] = *(const bf16x8*)(Kb + 1024 + koff0);
        kf[1][1] = *(const bf16x8*)(Kb + 1024 + koff1);

        #pragma unroll
        for (int pr = 0; pr < 2; pr++) {
            // ---- MFMA cluster: QK(pair pr) + PV(pair pr-1), independent ----
            __builtin_amdgcn_s_setprio(1);
            f32x4 z[2][2];   // [jj][i]
            #pragma unroll
            for (int jj = 0; jj < 2; jj++)
                #pragma unroll
                for (int i = 0; i < 2; i++) {
                    z[jj][i] = (f32x4){0.f, 0.f, 0.f, 0.f};
                    z[jj][i] = __builtin_amdgcn_mfma_f32_16x16x32_bf16(kf[jj][0], qf[i][0], z[jj][i], 0, 0, 0);
                    z[jj][i] = __builtin_amdgcn_mfma_f32_16x16x32_bf16(kf[jj][1], qf[i][1], z[jj][i], 0, 0, 0);
                }
            #pragma unroll
            for (int n = 0; n < 4; n++)
                #pragma unroll
                for (int i = 0; i < 2; i++)
                    o_t[n][i] = __builtin_amdgcn_mfma_f32_16x16x32_bf16(vfp[n], pfp[i], o_t[n][i], 0, 0, 0);
            __builtin_amdgcn_s_setprio(0);

            // ---- issue next-stage LDS reads (latency hidden by exp2 below) ----
            if (pr == 0) {   // K fragments for pair 1 (j-blocks 2,3)
                kf[0][0] = *(const bf16x8*)(Kb + 2048 + koff0);
                kf[0][1] = *(const bf16x8*)(Kb + 2048 + koff1);
                kf[1][0] = *(const bf16x8*)(Kb + 3072 + koff0);
                kf[1][1] = *(const bf16x8*)(Kb + 3072 + koff1);
            }
            // V^T fragments for THIS pair: two b64 chunks -> one K=32 A-frag
            bf16x8 vf[4];
            const int cb0 = ((pr * 4 + (quad >> 1)) ^ sw) * 8 + voff;
            const int cb1 = ((pr * 4 + 2 + (quad >> 1)) ^ sw) * 8 + voff;
            #pragma unroll
            for (int n = 0; n < 4; n++) {
                union { bf16x8 v8; s16x4 v4[2]; } u;
                u.v4[0] = *(const s16x4*)(Vb + n * 1024 + vrow + cb0);
                u.v4[1] = *(const s16x4*)(Vb + n * 1024 + vrow + cb1);
                vf[n] = u.v8;
            }
            __builtin_amdgcn_sched_barrier(0);   // VALU below may not float up

            // ---- softmax finish of z(pr): VALU overlaps MFMA + LDS pipes ----
            bf16x8 pf[2];
            #pragma unroll
            for (int i = 0; i < 2; i++) {
                bf16x8 pb;
                #pragma unroll
                for (int e = 0; e < 4; e++) {
                    float p0v = __builtin_amdgcn_exp2f(z[0][i][e]);
                    float p1v = __builtin_amdgcn_exp2f(z[1][i][e]);
                    if (e & 1) rsB[i] += p0v + p1v; else rsA[i] += p0v + p1v;
                    pb[e]     = (__bf16)p0v;
                    pb[e + 4] = (__bf16)p1v;
                }
                pf[i] = pb;
            }
            // rotate pipeline state (renamed away by full unroll)
            #pragma unroll
            for (int n = 0; n < 4; n++) vfp[n] = vf[n];
            pfp[0] = pf[0]; pfp[1] = pf[1];
        }
        p ^= 1;
    }

    // drain: final PV
    #pragma unroll
    for (int n = 0; n < 4; n++)
        #pragma unroll
        for (int i = 0; i < 2; i++)
            o_t[n][i] = __builtin_amdgcn_mfma_f32_16x16x32_bf16(vfp[n], pfp[i], o_t[n][i], 0, 0, 0);

    // epilogue: reduce denominators, normalize, write (layout unchanged)
    float inv_li[2];
    #pragma unroll
    for (int i = 0; i < 2; i++) {
        float t = rsA[i] + rsB[i];
        t += __shfl_xor(t, 16);
        t += __shfl_xor(t, 32);
        inv_li[i] = 1.f / t;
    }
    #pragma unroll
    for (int n = 0; n < 4; n++)
        #pragma unroll
        for (int i = 0; i < 2; i++) {
            int q = qt * 128 + wave * 32 + i * 16 + ln;
            int d = n * 16 + quad * 4;
            uint2 w;
            w.x = pkbf(o_t[n][i][0] * inv_li[i], o_t[n][i][1] * inv_li[i]);
            w.y = pkbf(o_t[n][i][2] * inv_li[i], o_t[n][i][3] * inv_li[i]);
            *(uint2*)(aws + ((size_t)b * S_LEN + q) * (NHEADS * HDIM) + h * HDIM + d) = w;
        }
}

// ---------------------------------------------------------------------------
// Kernel 3: output projection GEMM (NT) + bias. BK=64, swizzled. fp32 out.
// grid(64,8): mblk fast axis -> per-XCD working set 2 MB A + 2 MB Wo = L2 fit.
// ---------------------------------------------------------------------------
__global__ __launch_bounds__(256, 3)
void proj_kernel(const U16* __restrict__ A, const U16* __restrict__ Wob,
                 const float* __restrict__ bo, float* __restrict__ out)
{
    __shared__ __align__(16) U16 Asm[128 * 64];
    __shared__ __align__(16) U16 Bsm[128 * 64];

    const int mblk = blockIdx.x;   // 0..63 (fast axis)
    const int nblk = blockIdx.y;   // 0..7
    const int tid  = threadIdx.x;
    const int wave = tid >> 6, lane = tid & 63;
    const int ln = lane & 15, quad = lane >> 4;
    const int wm = wave >> 1, wn = wave & 1;

    const int nbase = nblk * 128;
    const U16* Wp = Wob + (size_t)nbase * HIDDEN;
    const U16* Ap = A + (size_t)mblk * 128 * HIDDEN;

    f32x4 acc[4][4];
    #pragma unroll
    for (int i = 0; i < 4; i++)
        #pragma unroll
        for (int j = 0; j < 4; j++) acc[i][j] = (f32x4){0.f, 0.f, 0.f, 0.f};

    const int l8 = lane >> 3;
    const int cg = (lane & 7) ^ l8;
    const int sw = ln & 7;

    for (int k0 = 0; k0 < HIDDEN; k0 += 64) {
        __syncthreads();
        #pragma unroll
        for (int t = 0; t < 4; t++) {
            int rbase = wave * 32 + t * 8;
            glds16(Ap + (size_t)(rbase + l8) * HIDDEN + k0 + cg * 8, &Asm[rbase * 64]);
            glds16(Wp + (size_t)(rbase + l8) * HIDDEN + k0 + cg * 8, &Bsm[rbase * 64]);
        }
        __syncthreads();

        bf16x8 af[4][2], bfr[4][2];
        #pragma unroll
        for (int i = 0; i < 4; i++)
            #pragma unroll
            for (int ks = 0; ks < 2; ks++) {
                af[i][ks]  = *(const bf16x8*)(&Asm[(wm * 64 + i * 16 + ln) * 64 + (((ks * 4 + quad) ^ sw) * 8)]);
                bfr[i][ks] = *(const bf16x8*)(&Bsm[(wn * 64 + i * 16 + ln) * 64 + (((ks * 4 + quad) ^ sw) * 8)]);
            }
        #pragma unroll
        for (int i = 0; i < 4; i++)
            #pragma unroll
            for (int j = 0; j < 4; j++) {
                acc[i][j] = __builtin_amdgcn_mfma_f32_16x16x32_bf16(af[i][0], bfr[j][0], acc[i][j], 0, 0, 0);
                acc[i][j] = __builtin_amdgcn_mfma_f32_16x16x32_bf16(af[i][1], bfr[j][1], acc[i][j], 0, 0, 0);
            }
    }

    float bias[4];
    #pragma unroll
    for (int j = 0; j < 4; j++) bias[j] = bo[nbase + wn * 64 + j * 16 + ln];

    #pragma unroll
    for (int i = 0; i < 4; i++)
        #pragma unroll
        for (int r = 0; r < 4; r++) {
            int m = mblk * 128 + wm * 64 + i * 16 + quad * 4 + r;
            #pragma unroll
            for (int j = 0; j < 4; j++) {
                int n = nbase + wn * 64 + j * 16 + ln;
                out[(size_t)m * HIDDEN + n] = acc[i][j][r] + bias[j];
            }
        }
}

// ---------------------------------------------------------------------------
extern "C" void kernel_launch(void* const* d_in, const int* in_sizes, int n_in,
                              void* d_out, int out_size, void* d_ws, size_t ws_size,
                              hipStream_t stream)
{
    const float* X    = (const float*)d_in[0];
    const float* cosT = (const float*)d_in[1];
    const float* sinT = (const float*)d_in[2];
    const float* Wq   = (const float*)d_in[3];
    const float* bq   = (const float*)d_in[4];
    const float* Wk   = (const float*)d_in[5];
    const float* bk   = (const float*)d_in[6];
    const float* Wv   = (const float*)d_in[7];
    const float* bv   = (const float*)d_in[8];
    const float* Wo   = (const float*)d_in[9];
    const float* bo   = (const float*)d_in[10];
    float* out = (float*)d_out;

    U16* wsb = (U16*)d_ws;
    U16* Xb   = wsb + OFF_XB;
    U16* Wqb  = wsb + OFF_WQB;
    U16* Wkb  = wsb + OFF_WKB;
    U16* Wvb  = wsb + OFF_WVB;
    U16* Wob  = wsb + OFF_WOB;
    U16* qws  = wsb + OFF_Q;
    U16* kws  = wsb + OFF_K;
    U16* vtws = wsb + OFF_V;
    U16* aws  = wsb + OFF_AWS;

    conv_kernel<<<dim3(10752), 256, 0, stream>>>(X, Wq, Wk, Wv, Wo, wsb);
    qkv_kernel<<<dim3(64, 12), 256, 0, stream>>>(Xb, Wqb, Wkb, Wvb, bq, bk, bv, cosT, sinT, qws, kws, vtws);
    attn_kernel<<<dim3(16, 64), 256, 0, stream>>>(qws, kws, vtws, aws);
    proj_kernel<<<dim3(64, 8), 256, 0, stream>>>(aws, Wob, bo, out);
}

// Round 7
// 239.245 us; speedup vs baseline: 1.1236x; 1.1236x over previous
//
#include <hip/hip_runtime.h>
#include <stdint.h>

#define S_LEN 2048
#define HIDDEN 1024
#define NHEADS 16
#define NKVH 4
#define HDIM 64

typedef __bf16 bf16x8 __attribute__((ext_vector_type(8)));
typedef __bf16 bf16x4 __attribute__((ext_vector_type(4)));
typedef float f32x4 __attribute__((ext_vector_type(4)));
typedef short s16x4 __attribute__((ext_vector_type(4)));
typedef unsigned short U16;

// ---- workspace layout (bf16 elems) -----------------------------------------
#define OFF_XB   0u          // 8192*1024 (aliased by aws later)
#define OFF_WQB  8388608u
#define OFF_WKB  9437184u
#define OFF_WVB  9699328u
#define OFF_WOB  9961472u
#define OFF_Q    11010048u
#define OFF_K    19398656u
#define OFF_V    21495808u   // V^T TILED: [b][hkv][s>>6][d][s&63]  (8KB-contiguous tiles)
#define OFF_AWS  OFF_XB

static __device__ __forceinline__ U16 f2bf(float f){
    unsigned u;
    __builtin_memcpy(&u, &f, 4);
    u += 0x7FFFu + ((u >> 16) & 1u);   // RNE
    return (U16)(u >> 16);
}
static __device__ __forceinline__ uint32_t pkbf(float lo, float hi){
    uint32_t a, b;
    __builtin_memcpy(&a, &lo, 4); a += 0x7FFFu + ((a >> 16) & 1u);
    __builtin_memcpy(&b, &hi, 4); b += 0x7FFFu + ((b >> 16) & 1u);
    return (a >> 16) | (b & 0xFFFF0000u);
}

typedef __attribute__((address_space(3))) uint32_t lds_u32;
typedef const __attribute__((address_space(1))) uint32_t glb_u32;
static __device__ __forceinline__ void glds16(const U16* g, U16* l){
    __builtin_amdgcn_global_load_lds((glb_u32*)g, (lds_u32*)l, 16, 0, 0);
}

// ---------------------------------------------------------------------------
// Kernel 0: fp32 -> bf16 convert of X, Wq, Wk, Wv, Wo into workspace.
// ---------------------------------------------------------------------------
__global__ void conv_kernel(const float* __restrict__ X,  const float* __restrict__ Wq,
                            const float* __restrict__ Wk, const float* __restrict__ Wv,
                            const float* __restrict__ Wo, U16* __restrict__ dst)
{
    size_t i4 = (size_t)blockIdx.x * 256 + threadIdx.x;
    size_t e = i4 * 4;
    const float* s;
    if (e < 8388608u)       s = X  + e;
    else if (e < 9437184u)  s = Wq + (e - 8388608u);
    else if (e < 9699328u)  s = Wk + (e - 9437184u);
    else if (e < 9961472u)  s = Wv + (e - 9699328u);
    else                    s = Wo + (e - 9961472u);
    float4 v = *(const float4*)s;
    uint2 o; o.x = pkbf(v.x, v.y); o.y = pkbf(v.z, v.w);
    *(uint2*)(dst + e) = o;
}

// ---------------------------------------------------------------------------
// Kernel 1: QKV GEMM (NT) + bias + RoPE. BK=64, glds16 + XOR chunk-swizzle.
// grid(64,12): mblk fast axis -> XCD partition for L2 locality.
// Q pre-scaled by 0.125*log2(e). V written to TILED-transposed ws.
//
// ROUND 7: overlap staging with compute WITHOUT extra LDS. Old structure was
// [barrier; glds(k); barrier(vmcnt drain = full glds latency exposed);
// compute(k)]. New: [barrier(glds k done -- issued a whole MFMA-phase ago);
// ds_read all fragments; barrier(LDS free, nothing in vmcnt); glds(k+1);
// sched_barrier; MFMAs]. The glds flies under the 32-MFMA cluster.
// ---------------------------------------------------------------------------
__global__ __launch_bounds__(256, 3)
void qkv_kernel(const U16* __restrict__ Xb,
                const U16* __restrict__ Wqb, const U16* __restrict__ Wkb, const U16* __restrict__ Wvb,
                const float* __restrict__ bq, const float* __restrict__ bk, const float* __restrict__ bv,
                const float* __restrict__ cosT, const float* __restrict__ sinT,
                U16* __restrict__ qws, U16* __restrict__ kws, U16* __restrict__ vtws)
{
    __shared__ __align__(16) U16 Asm[128 * 64];
    __shared__ __align__(16) U16 Bsm[128 * 64];

    const int mblk = blockIdx.x;   // 0..63  (fast axis -> XCD partition)
    const int nblk = blockIdx.y;   // 0..11
    const int tid  = threadIdx.x;
    const int wave = tid >> 6, lane = tid & 63;
    const int ln = lane & 15, quad = lane >> 4;
    const int wm = wave >> 1, wn = wave & 1;

    const U16* Wp; const float* biasp; int region;
    const int nbase = nblk * 128;
    if (nblk < 8)       { Wp = Wqb + (size_t)nbase * HIDDEN;          biasp = bq + nbase;          region = 0; }
    else if (nblk < 10) { Wp = Wkb + (size_t)(nbase - 1024) * HIDDEN; biasp = bk + (nbase - 1024); region = 1; }
    else                { Wp = Wvb + (size_t)(nbase - 1280) * HIDDEN; biasp = bv + (nbase - 1280); region = 2; }
    const U16* Xp = Xb + (size_t)mblk * 128 * HIDDEN;

    f32x4 acc[4][4];
    #pragma unroll
    for (int i = 0; i < 4; i++)
        #pragma unroll
        for (int j = 0; j < 4; j++) acc[i][j] = (f32x4){0.f, 0.f, 0.f, 0.f};

    const int l8 = lane >> 3;
    const int cg = (lane & 7) ^ l8;
    const int sw = ln & 7;

    // prologue: stage K-tile 0
    #pragma unroll
    for (int t = 0; t < 4; t++) {
        int rbase = wave * 32 + t * 8;
        glds16(Xp + (size_t)(rbase + l8) * HIDDEN + cg * 8, &Asm[rbase * 64]);
        glds16(Wp + (size_t)(rbase + l8) * HIDDEN + cg * 8, &Bsm[rbase * 64]);
    }

    for (int k0 = 0; k0 < HIDDEN; k0 += 64) {
        __syncthreads();   // glds(k0) complete (issued one MFMA-phase ago)

        bf16x8 af[4][2], bfr[4][2];
        #pragma unroll
        for (int i = 0; i < 4; i++)
            #pragma unroll
            for (int ks = 0; ks < 2; ks++) {
                af[i][ks]  = *(const bf16x8*)(&Asm[(wm * 64 + i * 16 + ln) * 64 + (((ks * 4 + quad) ^ sw) * 8)]);
                bfr[i][ks] = *(const bf16x8*)(&Bsm[(wn * 64 + i * 16 + ln) * 64 + (((ks * 4 + quad) ^ sw) * 8)]);
            }
        __syncthreads();   // fragments in regs; LDS free (vmcnt empty here)

        if (k0 + 64 < HIDDEN) {   // stage k0+1 -- flies under the MFMAs below
            #pragma unroll
            for (int t = 0; t < 4; t++) {
                int rbase = wave * 32 + t * 8;
                glds16(Xp + (size_t)(rbase + l8) * HIDDEN + (k0 + 64) + cg * 8, &Asm[rbase * 64]);
                glds16(Wp + (size_t)(rbase + l8) * HIDDEN + (k0 + 64) + cg * 8, &Bsm[rbase * 64]);
            }
        }
        __builtin_amdgcn_sched_barrier(0);   // glds must issue BEFORE the MFMAs

        #pragma unroll
        for (int i = 0; i < 4; i++)
            #pragma unroll
            for (int j = 0; j < 4; j++) {
                acc[i][j] = __builtin_amdgcn_mfma_f32_16x16x32_bf16(af[i][0], bfr[j][0], acc[i][j], 0, 0, 0);
                acc[i][j] = __builtin_amdgcn_mfma_f32_16x16x32_bf16(af[i][1], bfr[j][1], acc[i][j], 0, 0, 0);
            }
    }

    float bias[4];
    #pragma unroll
    for (int j = 0; j < 4; j++) bias[j] = biasp[wn * 64 + j * 16 + ln];

    const float QSCALE = 0.125f * 1.44269504089f;

    if (region == 2) {
        // V -> tiled transposed ws: r-index = consecutive s -> 8B coalesced stores
        #pragma unroll
        for (int i = 0; i < 4; i++) {
            int m0 = mblk * 128 + wm * 64 + i * 16 + quad * 4;   // r=0 row
            int b = m0 >> 11;
            int st6 = m0 & (S_LEN - 1);
            int tile = st6 >> 6, soff = st6 & 63;
            #pragma unroll
            for (int j = 0; j < 4; j++) {
                int n2 = nbase - 1280 + wn * 64 + j * 16 + ln;
                int hh = n2 >> 6, d = n2 & 63;
                uint2 w;
                w.x = pkbf(acc[i][j][0] + bias[j], acc[i][j][1] + bias[j]);
                w.y = pkbf(acc[i][j][2] + bias[j], acc[i][j][3] + bias[j]);
                *(uint2*)(vtws + ((((size_t)b * NKVH + hh) * 32 + tile) * 64 + d) * 64 + soff) = w;
            }
        }
    } else {
        #pragma unroll
        for (int i = 0; i < 4; i++) {
            #pragma unroll
            for (int r = 0; r < 4; r++) {
                int m = mblk * 128 + wm * 64 + i * 16 + quad * 4 + r;
                int s = m & (S_LEN - 1), b = m >> 11;
                float vals[4];
                #pragma unroll
                for (int j = 0; j < 4; j++) vals[j] = acc[i][j][r] + bias[j];
                float outv[4];
                #pragma unroll
                for (int j = 0; j < 4; j++) {
                    int d = (wn * 64 + j * 16 + ln) & 63;
                    float c  = cosT[s * HDIM + d];
                    float sn = sinT[s * HDIM + d];
                    float partner = vals[j ^ 2];
                    float rot = (d < 32) ? -partner : partner;
                    outv[j] = vals[j] * c + rot * sn;
                }
                if (region == 0) {  // Q (scaled)
                    #pragma unroll
                    for (int j = 0; j < 4; j++) {
                        int n = nbase + wn * 64 + j * 16 + ln;
                        int hh = n >> 6, d = n & 63;
                        qws[(((size_t)b * NHEADS + hh) * S_LEN + s) * HDIM + d] = f2bf(outv[j] * QSCALE);
                    }
                } else {            // K
                    #pragma unroll
                    for (int j = 0; j < 4; j++) {
                        int n2 = nbase - 1024 + wn * 64 + j * 16 + ln;
                        int hh = n2 >> 6, d = n2 & 63;
                        kws[(((size_t)b * NKVH + hh) * S_LEN + s) * HDIM + d] = f2bf(outv[j]);
                    }
                }
            }
        }
    }
}

// ---------------------------------------------------------------------------
// Kernel 2: flash attention, fixed-max softmax. QBLK=128, 64-key tiles,
// glds16-staged double-buffered K/V^T, ONE barrier/tile. grid (16, 64).
// EXACT R4 kernel (best measured: 96.4us). K=32-PV experiments (R5/R6) both
// regressed despite -1/3 matrix-pipe work -- abandoned.
// Pipeline: [QK(j)+PV(j-1) MFMA cluster, setprio] -> [LDS reads next stage]
// -> [sched_barrier] -> [exp2/pack of z(j)].
// ---------------------------------------------------------------------------
__global__ __launch_bounds__(256, 4)
void attn_kernel(const U16* __restrict__ qws, const U16* __restrict__ kws,
                 const U16* __restrict__ vtws, U16* __restrict__ aws)
{
    __shared__ __align__(16) U16 Ksm[2][64 * 64];    // 16 KB
    __shared__ __align__(16) U16 VTsm[2][64 * 64];   // 16 KB

    const int qt = blockIdx.x;       // 0..15 (QBLK = 128)
    const int hg = blockIdx.y;
    const int b = hg >> 4, h = hg & 15, hkv = h >> 2;
    const U16* Qh  = qws  + (size_t)hg * S_LEN * HDIM;
    const U16* Kh  = kws  + (size_t)(b * NKVH + hkv) * S_LEN * HDIM;
    const U16* VTh = vtws + (size_t)(b * NKVH + hkv) * HDIM * S_LEN;   // 32 tiles x 4096

    const int tid = threadIdx.x;
    const int wave = tid >> 6, lane = tid & 63;
    const int ln = lane & 15, quad = lane >> 4;
    const int sw = ln & 7;
    const int voff = (quad & 1) * 4;

    // Q fragments (B-operand, resident): two 16-row blocks per wave
    bf16x8 qf[2][2];
    #pragma unroll
    for (int i = 0; i < 2; i++)
        #pragma unroll
        for (int ks = 0; ks < 2; ks++) {
            int row = qt * 128 + wave * 32 + i * 16 + ln;
            qf[i][ks] = *(const bf16x8*)(Qh + (size_t)row * HDIM + ks * 32 + quad * 8);
        }

    float rsA[2] = {0.f, 0.f}, rsB[2] = {0.f, 0.f};
    f32x4 o_t[4][2];
    #pragma unroll
    for (int n = 0; n < 4; n++)
        #pragma unroll
        for (int i = 0; i < 2; i++) o_t[n][i] = (f32x4){0.f, 0.f, 0.f, 0.f};

    const int l8 = lane >> 3;
    const int cgk = (lane & 7) ^ l8;

    // loop-invariant per-lane LDS element offsets
    const int koff0 = ln * 64 + ((quad ^ sw) * 8);           // + j*1024
    const int koff1 = ln * 64 + (((quad + 4) ^ sw) * 8);     // + j*1024
    const int vbase = ln * 64 + voff;                         // + cvo[j] + n*1024
    int cvo[4];
    #pragma unroll
    for (int j = 0; j < 4; j++) cvo[j] = (((j * 2 + (quad >> 1)) ^ sw) * 8);

    // incremental glds source pointers (tile stride = 4096 elems both)
    const U16* pk[2]; const U16* pv[2];
    U16* dK[2]; U16* dV[2];
    #pragma unroll
    for (int t = 0; t < 2; t++) {
        int c = wave * 2 + t;
        pk[t] = Kh  + (size_t)(c * 8 + l8) * HDIM + cgk * 8;
        pv[t] = VTh + (size_t)(c * 8 + l8) * 64  + cgk * 8;
        dK[t] = &Ksm[0][c * 8 * 64];
        dV[t] = &VTsm[0][c * 8 * 64];
    }

    // prologue: stage tile 0
    #pragma unroll
    for (int t = 0; t < 2; t++) {
        glds16(pk[t], dK[t]);
        glds16(pv[t], dV[t]);
        pk[t] += 4096; pv[t] += 4096;
    }

    // software-pipeline state (zero-primed: first PV accumulates 0)
    s16x4 pfp[2];
    pfp[0] = (s16x4){0, 0, 0, 0}; pfp[1] = (s16x4){0, 0, 0, 0};
    s16x4 vfp[4];
    #pragma unroll
    for (int n = 0; n < 4; n++) vfp[n] = (s16x4){0, 0, 0, 0};

    int p = 0;
    for (int kt = 0; kt < 32; kt++) {
        __syncthreads();   // drains glds (tile kt ready in [p]); [p^1] free

        if (kt < 31) {     // prefetch tile kt+1 (flies under compute)
            #pragma unroll
            for (int t = 0; t < 2; t++) {
                glds16(pk[t], dK[t] + (p ^ 1) * 4096);
                glds16(pv[t], dV[t] + (p ^ 1) * 4096);
                pk[t] += 4096; pv[t] += 4096;
            }
        }

        const U16* Kb = &Ksm[p][0];
        const U16* Vb = &VTsm[p][0];

        // preload K fragments for j=0 (once-per-tile latency, amortized)
        bf16x8 kfa = *(const bf16x8*)(Kb + koff0);
        bf16x8 kfb = *(const bf16x8*)(Kb + koff1);

        #pragma unroll
        for (int j = 0; j < 4; j++) {
            // ---- MFMA cluster: QK(j) + PV(j-1), mutually independent ----
            __builtin_amdgcn_s_setprio(1);
            f32x4 z[2];
            #pragma unroll
            for (int i = 0; i < 2; i++) {
                z[i] = (f32x4){0.f, 0.f, 0.f, 0.f};
                z[i] = __builtin_amdgcn_mfma_f32_16x16x32_bf16(kfa, qf[i][0], z[i], 0, 0, 0);
                z[i] = __builtin_amdgcn_mfma_f32_16x16x32_bf16(kfb, qf[i][1], z[i], 0, 0, 0);
            }
            #pragma unroll
            for (int n = 0; n < 4; n++)
                #pragma unroll
                for (int i = 0; i < 2; i++)
                    o_t[n][i] = __builtin_amdgcn_mfma_f32_16x16x16bf16_1k(vfp[n], pfp[i], o_t[n][i], 0, 0, 0);
            __builtin_amdgcn_s_setprio(0);

            // ---- issue next-stage LDS reads (latency hidden by exp2 below) ----
            if (j < 3) {
                kfa = *(const bf16x8*)(Kb + (j + 1) * 1024 + koff0);
                kfb = *(const bf16x8*)(Kb + (j + 1) * 1024 + koff1);
            }
            s16x4 vf[4];
            const U16* Vj = Vb + vbase + cvo[j];
            #pragma unroll
            for (int n = 0; n < 4; n++)
                vf[n] = *(const s16x4*)(Vj + n * 1024);
            __builtin_amdgcn_sched_barrier(0);   // VALU below may not float up

            // ---- softmax finish of z(j): VALU overlaps MFMA + LDS pipes ----
            s16x4 pf[2];
            #pragma unroll
            for (int i = 0; i < 2; i++) {
                bf16x4 pb;
                #pragma unroll
                for (int r = 0; r < 4; r++) {
                    float pe = __builtin_amdgcn_exp2f(z[i][r]);
                    if (r & 1) rsB[i] += pe; else rsA[i] += pe;
                    pb[r] = (__bf16)pe;
                }
                __builtin_memcpy(&pf[i], &pb, 8);
            }
            // rotate pipeline state (renamed away by full unroll)
            #pragma unroll
            for (int n = 0; n < 4; n++) vfp[n] = vf[n];
            pfp[0] = pf[0]; pfp[1] = pf[1];
        }
        p ^= 1;
    }

    // drain: final PV
    #pragma unroll
    for (int n = 0; n < 4; n++)
        #pragma unroll
        for (int i = 0; i < 2; i++)
            o_t[n][i] = __builtin_amdgcn_mfma_f32_16x16x16bf16_1k(vfp[n], pfp[i], o_t[n][i], 0, 0, 0);

    // epilogue: reduce denominators, normalize, write
    float inv_li[2];
    #pragma unroll
    for (int i = 0; i < 2; i++) {
        float t = rsA[i] + rsB[i];
        t += __shfl_xor(t, 16);
        t += __shfl_xor(t, 32);
        inv_li[i] = 1.f / t;
    }
    #pragma unroll
    for (int n = 0; n < 4; n++)
        #pragma unroll
        for (int i = 0; i < 2; i++) {
            int q = qt * 128 + wave * 32 + i * 16 + ln;
            int d = n * 16 + quad * 4;
            uint2 w;
            w.x = pkbf(o_t[n][i][0] * inv_li[i], o_t[n][i][1] * inv_li[i]);
            w.y = pkbf(o_t[n][i][2] * inv_li[i], o_t[n][i][3] * inv_li[i]);
            *(uint2*)(aws + ((size_t)b * S_LEN + q) * (NHEADS * HDIM) + h * HDIM + d) = w;
        }
}

// ---------------------------------------------------------------------------
// Kernel 3: output projection GEMM (NT) + bias. BK=64, swizzled. fp32 out.
// grid(64,8). ROUND 7: same stage-under-compute overlap as qkv.
// ---------------------------------------------------------------------------
__global__ __launch_bounds__(256, 3)
void proj_kernel(const U16* __restrict__ A, const U16* __restrict__ Wob,
                 const float* __restrict__ bo, float* __restrict__ out)
{
    __shared__ __align__(16) U16 Asm[128 * 64];
    __shared__ __align__(16) U16 Bsm[128 * 64];

    const int mblk = blockIdx.x;   // 0..63 (fast axis)
    const int nblk = blockIdx.y;   // 0..7
    const int tid  = threadIdx.x;
    const int wave = tid >> 6, lane = tid & 63;
    const int ln = lane & 15, quad = lane >> 4;
    const int wm = wave >> 1, wn = wave & 1;

    const int nbase = nblk * 128;
    const U16* Wp = Wob + (size_t)nbase * HIDDEN;
    const U16* Ap = A + (size_t)mblk * 128 * HIDDEN;

    f32x4 acc[4][4];
    #pragma unroll
    for (int i = 0; i < 4; i++)
        #pragma unroll
        for (int j = 0; j < 4; j++) acc[i][j] = (f32x4){0.f, 0.f, 0.f, 0.f};

    const int l8 = lane >> 3;
    const int cg = (lane & 7) ^ l8;
    const int sw = ln & 7;

    // prologue: stage K-tile 0
    #pragma unroll
    for (int t = 0; t < 4; t++) {
        int rbase = wave * 32 + t * 8;
        glds16(Ap + (size_t)(rbase + l8) * HIDDEN + cg * 8, &Asm[rbase * 64]);
        glds16(Wp + (size_t)(rbase + l8) * HIDDEN + cg * 8, &Bsm[rbase * 64]);
    }

    for (int k0 = 0; k0 < HIDDEN; k0 += 64) {
        __syncthreads();   // glds(k0) complete

        bf16x8 af[4][2], bfr[4][2];
        #pragma unroll
        for (int i = 0; i < 4; i++)
            #pragma unroll
            for (int ks = 0; ks < 2; ks++) {
                af[i][ks]  = *(const bf16x8*)(&Asm[(wm * 64 + i * 16 + ln) * 64 + (((ks * 4 + quad) ^ sw) * 8)]);
                bfr[i][ks] = *(const bf16x8*)(&Bsm[(wn * 64 + i * 16 + ln) * 64 + (((ks * 4 + quad) ^ sw) * 8)]);
            }
        __syncthreads();   // fragments in regs; LDS free

        if (k0 + 64 < HIDDEN) {   // stage k0+1 under the MFMAs
            #pragma unroll
            for (int t = 0; t < 4; t++) {
                int rbase = wave * 32 + t * 8;
                glds16(Ap + (size_t)(rbase + l8) * HIDDEN + (k0 + 64) + cg * 8, &Asm[rbase * 64]);
                glds16(Wp + (size_t)(rbase + l8) * HIDDEN + (k0 + 64) + cg * 8, &Bsm[rbase * 64]);
            }
        }
        __builtin_amdgcn_sched_barrier(0);

        #pragma unroll
        for (int i = 0; i < 4; i++)
            #pragma unroll
            for (int j = 0; j < 4; j++) {
                acc[i][j] = __builtin_amdgcn_mfma_f32_16x16x32_bf16(af[i][0], bfr[j][0], acc[i][j], 0, 0, 0);
                acc[i][j] = __builtin_amdgcn_mfma_f32_16x16x32_bf16(af[i][1], bfr[j][1], acc[i][j], 0, 0, 0);
            }
    }

    float bias[4];
    #pragma unroll
    for (int j = 0; j < 4; j++) bias[j] = bo[nbase + wn * 64 + j * 16 + ln];

    #pragma unroll
    for (int i = 0; i < 4; i++)
        #pragma unroll
        for (int r = 0; r < 4; r++) {
            int m = mblk * 128 + wm * 64 + i * 16 + quad * 4 + r;
            #pragma unroll
            for (int j = 0; j < 4; j++) {
                int n = nbase + wn * 64 + j * 16 + ln;
                out[(size_t)m * HIDDEN + n] = acc[i][j][r] + bias[j];
            }
        }
}

// ---------------------------------------------------------------------------
extern "C" void kernel_launch(void* const* d_in, const int* in_sizes, int n_in,
                              void* d_out, int out_size, void* d_ws, size_t ws_size,
                              hipStream_t stream)
{
    const float* X    = (const float*)d_in[0];
    const float* cosT = (const float*)d_in[1];
    const float* sinT = (const float*)d_in[2];
    const float* Wq   = (const float*)d_in[3];
    const float* bq   = (const float*)d_in[4];
    const float* Wk   = (const float*)d_in[5];
    const float* bk   = (const float*)d_in[6];
    const float* Wv   = (const float*)d_in[7];
    const float* bv   = (const float*)d_in[8];
    const float* Wo   = (const float*)d_in[9];
    const float* bo   = (const float*)d_in[10];
    float* out = (float*)d_out;

    U16* wsb = (U16*)d_ws;
    U16* Xb   = wsb + OFF_XB;
    U16* Wqb  = wsb + OFF_WQB;
    U16* Wkb  = wsb + OFF_WKB;
    U16* Wvb  = wsb + OFF_WVB;
    U16* Wob  = wsb + OFF_WOB;
    U16* qws  = wsb + OFF_Q;
    U16* kws  = wsb + OFF_K;
    U16* vtws = wsb + OFF_V;
    U16* aws  = wsb + OFF_AWS;

    conv_kernel<<<dim3(10752), 256, 0, stream>>>(X, Wq, Wk, Wv, Wo, wsb);
    qkv_kernel<<<dim3(64, 12), 256, 0, stream>>>(Xb, Wqb, Wkb, Wvb, bq, bk, bv, cosT, sinT, qws, kws, vtws);
    attn_kernel<<<dim3(16, 64), 256, 0, stream>>>(qws, kws, vtws, aws);
    proj_kernel<<<dim3(64, 8), 256, 0, stream>>>(aws, Wob, bo, out);
}